// Round 10
// baseline (38.419 us; speedup 1.0000x reference)
//
#include <hip/hip_runtime.h>
#include <hip/hip_fp16.h>
#include <math.h>

// Problem constants: N=2000 politicians, B=2000 bills, D=32, K(order)=3.
#define NN    2000
#define NB    2000
#define DD    32
#define PAD   2048                 // padded N/B for tiling
#define NOCT  16                   // 128 k-elements / 8 per octet (96 data + 6 poly + pad)
#define TILE  64                   // block tile: 64 pols x 64 bills
#define GDIM  (PAD / TILE)         // 32
#define NPART (GDIM * GDIM)        // 1024 partials

typedef _Float16 half8  __attribute__((ext_vector_type(8)));
typedef float    float4v __attribute__((ext_vector_type(4)));

// d_ws layout (bytes):
#define ZF_OFF 0                                  // ZfF: [NOCT][PAD][8] f16 = 512KB
#define WF_OFF (NOCT * PAD * 8 * 2)               // WF:  same shape         512KB
#define PT_OFF (2 * (NOCT * PAD * 8 * 2))         // partials: float[NPART]    4KB
#define CT_OFF (PT_OFF + NPART * 4)               // counter: uint32           4B

// ---------------- prep: fragment-major fp16 operands with poly extension ---
// k layout (per n / per b), 128 wide:
//   k 0..31  : A_n          | z_b
//   k 32..63 : B_n          | t*z_b
//   k 64..95 : C_n          | (t^2/2)*z_b
//   k 96..103: [c0..c4,1,0,0] | [-.5, -.5t, -.5t^2, -.5t^3, -.5t^4, -.5|z|^2,0,0]
//   k 104..127: zeros
// => GEMM g[n][b] = dot - pv/2 - |z|^2/2 = -dist^2/2.
__global__ __launch_bounds__(256) void pol2vec_prep(
    const float* __restrict__ zb, const float* __restrict__ zp,
    const float* __restrict__ tarr,
    _Float16* __restrict__ ZfF, _Float16* __restrict__ WF)
{
    const int u = blockIdx.x * 256 + threadIdx.x;
    const int total = NOCT * PAD;
    float vals[8] = {0.f, 0.f, 0.f, 0.f, 0.f, 0.f, 0.f, 0.f};

    if (u < total) {                              // ----- Zf side
        const int o = u / PAD, b = u - o * PAD;
        if (b < NB) {
            if (o < 12) {
                const float t = tarr[b];
                const float s = (o < 4) ? 1.f : (o < 8) ? t : 0.5f * t * t;
                const float* zrow = zb + (size_t)b * DD + 8 * (o & 3);
#pragma unroll
                for (int i = 0; i < 8; ++i) vals[i] = s * zrow[i];
            } else if (o == 12) {
                const float t = tarr[b];
                const float* zrow = zb + (size_t)b * DD;
                float z2 = 0.f;
#pragma unroll
                for (int d = 0; d < DD; ++d) z2 = fmaf(zrow[d], zrow[d], z2);
                const float t2 = t * t;
                vals[0] = -0.5f;        vals[1] = -0.5f * t;
                vals[2] = -0.5f * t2;   vals[3] = -0.5f * t2 * t;
                vals[4] = -0.5f * t2 * t2;
                vals[5] = -0.5f * z2;
            }
        }
        _Float16* dst = ZfF + (size_t)u * 8;
#pragma unroll
        for (int i = 0; i < 8; ++i) dst[i] = (_Float16)vals[i];
    } else if (u < 2 * total) {                   // ----- W side
        const int u2 = u - total;
        const int o = u2 / PAD, n = u2 - o * PAD;
        if (n < NN) {
            if (o < 12) {
                const int ksel = o >> 2;          // 0:A 1:B 2:C
                const float* src = zp + ((size_t)ksel * NN + n) * DD + 8 * (o & 3);
#pragma unroll
                for (int i = 0; i < 8; ++i) vals[i] = src[i];
            } else if (o == 12) {
                const float* pA = zp + (size_t)n * DD;
                const float* pB = zp + ((size_t)NN + n) * DD;
                const float* pC = zp + ((size_t)2 * NN + n) * DD;
                float aa = 0.f, ab = 0.f, ac = 0.f, bb = 0.f, bc = 0.f, cc = 0.f;
#pragma unroll
                for (int d = 0; d < DD; ++d) {
                    const float a = pA[d], b = pB[d], c = pC[d];
                    aa = fmaf(a, a, aa); ab = fmaf(a, b, ab); ac = fmaf(a, c, ac);
                    bb = fmaf(b, b, bb); bc = fmaf(b, c, bc); cc = fmaf(c, c, cc);
                }
                vals[0] = aa;        vals[1] = 2.f * ab;
                vals[2] = bb + ac;   vals[3] = bc;
                vals[4] = 0.25f * cc;
                vals[5] = 1.f;
            }
        }
        _Float16* dst = WF + (size_t)u2 * 8;
#pragma unroll
        for (int i = 0; i < 8; ++i) dst[i] = (_Float16)vals[i];
    }
}

// ---------------- main: MFMA GEMM -> -dist^2/2, fused logistic epilogue,
// per-block partial, deterministic last-block final reduction (no 3rd kernel,
// no memset: counter uses mod-1024 detection, valid for any initial value).
__global__ __launch_bounds__(256, 4) void pol2vec_main(
    const int* __restrict__ events,           // [N,B] 0/1
    const _Float16* __restrict__ ZfF, const _Float16* __restrict__ WF,
    const float* __restrict__ gamma, const float* __restrict__ beta,
    float* __restrict__ partials, unsigned* __restrict__ counter,
    float* __restrict__ out)
{
    __shared__ float s_red[4];
    __shared__ int   s_last;

    const int tid  = threadIdx.x;
    const int lane = tid & 63;
    const int w    = tid >> 6;                // wave 0..3
    const int b0   = blockIdx.x * TILE;       // bill base
    const int n0   = blockIdx.y * TILE;       // politician base
    const int wr   = (w >> 1) * 32;           // wave's pol offset in tile
    const int wc   = (w & 1) * 32;            // wave's bill offset in tile
    const int l15  = lane & 15;
    const int l4   = lane >> 4;

    // Fragment loads: one coalesced 16B/lane load per fragment (4 K-steps).
    half8 af[2][4], bf[2][4];
#pragma unroll
    for (int ks = 0; ks < 4; ++ks) {
        const int oct = 4 * ks + l4;
#pragma unroll
        for (int h = 0; h < 2; ++h) {
            af[h][ks] = *(const half8*)(WF  + ((size_t)oct * PAD + (n0 + wr + 16 * h + l15)) * 8);
            bf[h][ks] = *(const half8*)(ZfF + ((size_t)oct * PAD + (b0 + wc + 16 * h + l15)) * 8);
        }
    }

    // Prefetch the 16 event words -> bitmasks (hides HBM latency under MFMA).
    unsigned evb = 0u, vb = 0u;
#pragma unroll
    for (int nr = 0; nr < 2; ++nr)
#pragma unroll
    for (int bc = 0; bc < 2; ++bc)
#pragma unroll
    for (int r = 0; r < 4; ++r) {
        const int ng = n0 + wr + 16 * nr + l4 * 4 + r;
        const int bg = b0 + wc + 16 * bc + l15;
        const bool v = (ng < NN) && (bg < NB);
        const size_t idx = v ? ((size_t)ng * NB + bg) : 0;
        const unsigned bit = 1u << (nr * 8 + bc * 4 + r);
        if (v) vb |= bit;
        if (v && events[idx]) evb |= bit;
    }

    float4v acc[2][2] = {};
#pragma unroll
    for (int nr = 0; nr < 2; ++nr)
#pragma unroll
    for (int bc = 0; bc < 2; ++bc)
#pragma unroll
    for (int ks = 0; ks < 4; ++ks)
        acc[nr][bc] = __builtin_amdgcn_mfma_f32_16x16x32_f16(
            af[nr][ks], bf[bc][ks], acc[nr][bc], 0, 0, 0);

    // Epilogue: acc = -dist^2/2.  L = gamma + beta - dist.
    float accs = 0.f;
#pragma unroll
    for (int bc = 0; bc < 2; ++bc) {
        const int bg = b0 + wc + 16 * bc + l15;
        const float be = beta[bg < NB ? bg : 0];          // coalesced 16-lane
#pragma unroll
        for (int nr = 0; nr < 2; ++nr) {
#pragma unroll
            for (int r = 0; r < 4; ++r) {
                const int ng = n0 + wr + 16 * nr + l4 * 4 + r;
                const float g = gamma[ng < NN ? ng : 0];  // group-broadcast
                const float d2 = fmaxf(-2.f * acc[nr][bc][r], 0.f);
                const float L  = g + be - sqrtf(d2);
                const unsigned bit = 1u << (nr * 8 + bc * 4 + r);
                const float sgn = (evb & bit) ? 1.f : -1.f;
                const float s   = sgn * L;
                const float term = fmaxf(-s, 0.f) + __logf(1.f + __expf(-fabsf(s)));
                accs += (vb & bit) ? term : 0.f;
            }
        }
    }

    // Block partial.
#pragma unroll
    for (int o = 32; o > 0; o >>= 1) accs += __shfl_down(accs, o, 64);
    if (lane == 0) s_red[w] = accs;
    __syncthreads();
    if (tid == 0) {
        partials[blockIdx.y * GDIM + blockIdx.x] =
            (s_red[0] + s_red[1]) + (s_red[2] + s_red[3]);
        __threadfence();                          // publish partial
        const unsigned old = atomicAdd(counter, 1u);
        s_last = ((old & (NPART - 1u)) == (NPART - 1u)) ? 1 : 0;
    }
    __syncthreads();

    // Deterministic final reduction by whichever block finished last
    // (fixed summation order -> bitwise-stable result).
    if (s_last) {
        __threadfence();                          // acquire all partials
        float s = 0.f;
        for (int i = tid; i < NPART; i += 256) s += partials[i];
#pragma unroll
        for (int o = 32; o > 0; o >>= 1) s += __shfl_down(s, o, 64);
        if (lane == 0) s_red[w] = s;
        __syncthreads();
        if (tid == 0)
            out[0] = (s_red[0] + s_red[1]) + (s_red[2] + s_red[3]);
    }
}

extern "C" void kernel_launch(void* const* d_in, const int* in_sizes, int n_in,
                              void* d_out, int out_size, void* d_ws, size_t ws_size,
                              hipStream_t stream) {
    const int*   events = (const int*)d_in[0];    // [N,B]
    const float* tarr   = (const float*)d_in[1];  // [B]
    const float* beta   = (const float*)d_in[2];  // [B]
    const float* gamma  = (const float*)d_in[3];  // [N]
    const float* zb     = (const float*)d_in[4];  // [B,D]
    const float* zp     = (const float*)d_in[5];  // [K,N,D]
    float* out = (float*)d_out;

    _Float16* ZfF   = (_Float16*)((char*)d_ws + ZF_OFF);
    _Float16* WF    = (_Float16*)((char*)d_ws + WF_OFF);
    float*    parts = (float*)((char*)d_ws + PT_OFF);
    unsigned* ctr   = (unsigned*)((char*)d_ws + CT_OFF);

    const int prep_units = 2 * NOCT * PAD;        // 65536
    pol2vec_prep<<<prep_units / 256, 256, 0, stream>>>(zb, zp, tarr, ZfF, WF);

    dim3 grid(GDIM, GDIM);
    pol2vec_main<<<grid, 256, 0, stream>>>(events, ZfF, WF, gamma, beta,
                                           parts, ctr, out);
}

// Round 11
// 26.274 us; speedup vs baseline: 1.4622x; 1.4622x over previous
//
#include <hip/hip_runtime.h>
#include <hip/hip_fp16.h>
#include <math.h>

// Problem constants: N=2000 politicians, B=2000 bills, D=32, K(order)=3.
#define NN    2000
#define NB    2000
#define DD    32
#define PAD   2048                 // padded N/B for tiling
#define NOCT  12                   // 96 k-elements / 8 per octet
#define TILE  64                   // block tile: 64 pols x 64 bills
#define GDIM  (PAD / TILE)         // 32
#define NPART (GDIM * GDIM)        // 1024 partials

typedef _Float16 half8   __attribute__((ext_vector_type(8)));
typedef float    float4v __attribute__((ext_vector_type(4)));

// ---------------- fused main: in-block operand build (LDS) + MFMA GEMM +
// logistic epilogue + block partial. No prep dispatch, no fences.
// dot[n][b] = A.z + t B.z + (t^2/2) C.z via fp16 MFMA (K=96);
// dist^2 = poly_n(t) - 2 dot + |z_b|^2 with fp32 poly coeffs from LDS.
__global__ __launch_bounds__(256, 4) void pol2vec_main(
    const int*   __restrict__ events,   // [N,B] 0/1
    const float* __restrict__ tarr,     // [B]
    const float* __restrict__ beta,     // [B]
    const float* __restrict__ gamma,    // [N]
    const float* __restrict__ zb,       // [B,D]
    const float* __restrict__ zp,       // [K,N,D]
    float*       __restrict__ partials) // [NPART]
{
    __shared__ _Float16 sW[NOCT * TILE * 8];   // 12KB  A/B/C fragment rows
    __shared__ _Float16 sZ[NOCT * TILE * 8];   // 12KB  z,tz,(t^2/2)z rows
    __shared__ float    sNP[TILE][8];          // 2KB   {c0..c4, gamma}
    __shared__ float    sBP[TILE][4];          // 1KB   {t, beta, |z|^2}
    __shared__ float    s_red[4];

    const int tid  = threadIdx.x;
    const int lane = tid & 63;
    const int w    = tid >> 6;                // wave 0..3
    const int b0   = blockIdx.x * TILE;       // bill base
    const int n0   = blockIdx.y * TILE;       // politician base
    const int wr   = (w >> 1) * 32;           // wave's pol offset in tile
    const int wc   = (w & 1) * 32;            // wave's bill offset in tile
    const int l15  = lane & 15;
    const int l4   = lane >> 4;

    // ---- Events gather first: issues 16 independent loads early so their
    // L3/HBM latency overlaps the whole LDS build phase.
    unsigned evb = 0u, vb = 0u;
#pragma unroll
    for (int nr = 0; nr < 2; ++nr)
#pragma unroll
    for (int bc = 0; bc < 2; ++bc)
#pragma unroll
    for (int r = 0; r < 4; ++r) {
        const int ng = n0 + wr + 16 * nr + l4 * 4 + r;
        const int bg = b0 + wc + 16 * bc + l15;
        const bool v = (ng < NN) && (bg < NB);
        const size_t idx = v ? ((size_t)ng * NB + bg) : 0;
        const unsigned bit = 1u << (nr * 8 + bc * 4 + r);
        if (v) vb |= bit;
        if (v && events[idx]) evb |= bit;
    }

    // ---- Build W fragments: oct 0-3 A, 4-7 B, 8-11 C (rows = pols).
    for (int u = tid; u < NOCT * TILE; u += 256) {
        const int oct = u >> 6, nl = u & 63;
        const int n = n0 + nl;
        half8 hv = {};
        if (n < NN) {
            const int ksel = oct >> 2;
            const float* src = zp + ((size_t)ksel * NN + n) * DD + 8 * (oct & 3);
            const float4 x = ((const float4*)src)[0];
            const float4 y = ((const float4*)src)[1];
            hv[0] = (_Float16)x.x; hv[1] = (_Float16)x.y;
            hv[2] = (_Float16)x.z; hv[3] = (_Float16)x.w;
            hv[4] = (_Float16)y.x; hv[5] = (_Float16)y.y;
            hv[6] = (_Float16)y.z; hv[7] = (_Float16)y.w;
        }
        *(half8*)(sW + (size_t)u * 8) = hv;
    }

    // ---- Build Zf fragments: oct 0-3 z, 4-7 t*z, 8-11 (t^2/2)*z (rows = bills).
    for (int u = tid; u < NOCT * TILE; u += 256) {
        const int oct = u >> 6, bl = u & 63;
        const int b = b0 + bl;
        half8 hv = {};
        if (b < NB) {
            const float t = tarr[b];
            const float s = (oct < 4) ? 1.f : (oct < 8) ? t : 0.5f * t * t;
            const float* src = zb + (size_t)b * DD + 8 * (oct & 3);
            const float4 x = ((const float4*)src)[0];
            const float4 y = ((const float4*)src)[1];
            hv[0] = (_Float16)(s * x.x); hv[1] = (_Float16)(s * x.y);
            hv[2] = (_Float16)(s * x.z); hv[3] = (_Float16)(s * x.w);
            hv[4] = (_Float16)(s * y.x); hv[5] = (_Float16)(s * y.y);
            hv[6] = (_Float16)(s * y.z); hv[7] = (_Float16)(s * y.w);
        }
        *(half8*)(sZ + (size_t)u * 8) = hv;
    }

    // ---- Param tables: tid<64 -> bill params; 64<=tid<128 -> pol coeffs.
    if (tid < TILE) {
        const int b = b0 + tid;
        float t = 0.f, be = 0.f, z2 = 0.f;
        if (b < NB) {
            t = tarr[b]; be = beta[b];
            const float* zrow = zb + (size_t)b * DD;
#pragma unroll
            for (int d = 0; d < DD; ++d) z2 = fmaf(zrow[d], zrow[d], z2);
        }
        sBP[tid][0] = t; sBP[tid][1] = be; sBP[tid][2] = z2; sBP[tid][3] = 0.f;
    } else if (tid < 2 * TILE) {
        const int nl = tid - TILE;
        const int n = n0 + nl;
        float c[6] = {0.f, 0.f, 0.f, 0.f, 0.f, 0.f};
        if (n < NN) {
            const float* pA = zp + (size_t)n * DD;
            const float* pB = zp + ((size_t)NN + n) * DD;
            const float* pC = zp + ((size_t)2 * NN + n) * DD;
            float aa = 0.f, ab = 0.f, ac = 0.f, bb = 0.f, bc = 0.f, cc = 0.f;
#pragma unroll
            for (int d = 0; d < DD; ++d) {
                const float a = pA[d], b = pB[d], cv = pC[d];
                aa = fmaf(a, a, aa); ab = fmaf(a, b, ab); ac = fmaf(a, cv, ac);
                bb = fmaf(b, b, bb); bc = fmaf(b, cv, bc); cc = fmaf(cv, cv, cc);
            }
            c[0] = aa;          c[1] = 2.f * ab;  c[2] = bb + ac;
            c[3] = bc;          c[4] = 0.25f * cc; c[5] = gamma[n];
        }
#pragma unroll
        for (int i = 0; i < 6; ++i) sNP[nl][i] = c[i];
        sNP[nl][6] = 0.f; sNP[nl][7] = 0.f;
    }

    __syncthreads();

    // ---- Fragment loads from LDS (same layout math as the proven r9 kernel).
    half8 af[2][3], bf[2][3];
#pragma unroll
    for (int ks = 0; ks < 3; ++ks) {
        const int oct = 4 * ks + l4;
#pragma unroll
        for (int h = 0; h < 2; ++h) {
            af[h][ks] = *(const half8*)(sW + ((size_t)oct * TILE + wr + 16 * h + l15) * 8);
            bf[h][ks] = *(const half8*)(sZ + ((size_t)oct * TILE + wc + 16 * h + l15) * 8);
        }
    }

    float4v acc[2][2] = {};
#pragma unroll
    for (int nr = 0; nr < 2; ++nr)
#pragma unroll
    for (int bc = 0; bc < 2; ++bc)
#pragma unroll
    for (int ks = 0; ks < 3; ++ks)
        acc[nr][bc] = __builtin_amdgcn_mfma_f32_16x16x32_f16(
            af[nr][ks], bf[bc][ks], acc[nr][bc], 0, 0, 0);

    // ---- Epilogue: dist^2 = pv - 2 dot + z2;  L = gamma + beta - dist.
    float accs = 0.f;
#pragma unroll
    for (int bc = 0; bc < 2; ++bc) {
        const int bl = wc + 16 * bc + l15;
        const float t  = sBP[bl][0];
        const float be = sBP[bl][1];
        const float z2 = sBP[bl][2];
#pragma unroll
        for (int nr = 0; nr < 2; ++nr) {
#pragma unroll
            for (int r = 0; r < 4; ++r) {
                const int nl = wr + 16 * nr + l4 * 4 + r;
                const float* cc = sNP[nl];
                const float dot = acc[nr][bc][r];
                const float pv = fmaf(t, fmaf(t, fmaf(t, fmaf(t, cc[4], cc[3]),
                                                      cc[2]), cc[1]), cc[0]);
                const float d2 = fmaxf(fmaf(-2.f, dot, pv + z2), 0.f);
                const float L  = cc[5] + be - sqrtf(d2);
                const unsigned bit = 1u << (nr * 8 + bc * 4 + r);
                const float sgn = (evb & bit) ? 1.f : -1.f;
                const float s   = sgn * L;
                const float term = fmaxf(-s, 0.f) + __logf(1.f + __expf(-fabsf(s)));
                accs += (vb & bit) ? term : 0.f;
            }
        }
    }

    // ---- Block partial.
#pragma unroll
    for (int o = 32; o > 0; o >>= 1) accs += __shfl_down(accs, o, 64);
    if (lane == 0) s_red[w] = accs;
    __syncthreads();
    if (tid == 0)
        partials[blockIdx.y * GDIM + blockIdx.x] =
            (s_red[0] + s_red[1]) + (s_red[2] + s_red[3]);
}

// ---------------- reduce: 1024 partials -> d_out[0] (overwrite) ------------
__global__ __launch_bounds__(256) void pol2vec_reduce(
    const float4* __restrict__ p4, float* __restrict__ out)
{
    __shared__ float s_red[4];
    const int tid = threadIdx.x;
    const float4 v = p4[tid];                 // 256 threads x float4 = 1024
    float s = (v.x + v.y) + (v.z + v.w);
#pragma unroll
    for (int o = 32; o > 0; o >>= 1) s += __shfl_down(s, o, 64);
    if ((tid & 63) == 0) s_red[tid >> 6] = s;
    __syncthreads();
    if (tid == 0) out[0] = (s_red[0] + s_red[1]) + (s_red[2] + s_red[3]);
}

extern "C" void kernel_launch(void* const* d_in, const int* in_sizes, int n_in,
                              void* d_out, int out_size, void* d_ws, size_t ws_size,
                              hipStream_t stream) {
    const int*   events = (const int*)d_in[0];    // [N,B]
    const float* tarr   = (const float*)d_in[1];  // [B]
    const float* beta   = (const float*)d_in[2];  // [B]
    const float* gamma  = (const float*)d_in[3];  // [N]
    const float* zb     = (const float*)d_in[4];  // [B,D]
    const float* zp     = (const float*)d_in[5];  // [K,N,D]
    float* out = (float*)d_out;

    float* parts = (float*)d_ws;                  // [NPART], overwritten

    dim3 grid(GDIM, GDIM);
    pol2vec_main<<<grid, 256, 0, stream>>>(events, tarr, beta, gamma, zb, zp,
                                           parts);
    pol2vec_reduce<<<1, 256, 0, stream>>>((const float4*)parts, out);
}

// Round 12
// 25.188 us; speedup vs baseline: 1.5253x; 1.0431x over previous
//
#include <hip/hip_runtime.h>
#include <hip/hip_fp16.h>
#include <math.h>

// Problem constants: N=2000 politicians, B=2000 bills, D=32, K(order)=3.
#define NN    2000
#define NB    2000
#define DD    32
#define NOCT  16                   // K=128: 12 data octets + poly octet + 3 zero
#define TILE  64                   // block tile: 64 pols x 64 bills
#define GDIM  32                   // 2048/64
#define NPART (GDIM * GDIM)        // 1024 partials

typedef _Float16 half8   __attribute__((ext_vector_type(8)));
typedef float    float4v __attribute__((ext_vector_type(4)));

// Fused main: in-block coalesced operand build (LDS) + fp16 MFMA K=128 giving
// -dist^2/2 directly + logistic epilogue + block partial. 2 dispatches total.
__global__ __launch_bounds__(256, 4) void pol2vec_main(
    const int*   __restrict__ events,   // [N,B] 0/1
    const float* __restrict__ tarr,     // [B]
    const float* __restrict__ beta,     // [B]
    const float* __restrict__ gamma,    // [N]
    const float* __restrict__ zb,       // [B,D]
    const float* __restrict__ zp,       // [K,N,D]
    float*       __restrict__ partials) // [NPART]
{
    __shared__ _Float16 sW[NOCT * TILE * 8];   // 16KB: A,B,C octs + [c0..c4,1]
    __shared__ _Float16 sZ[NOCT * TILE * 8];   // 16KB: z,tz,t2/2 z + poly row
    __shared__ float    sT[TILE][4][6];        // 6KB  pol-coeff partials
    __shared__ float    sT2[TILE][4];          // 1KB  z2 partials
    __shared__ float    s_red[4];

    const int tid  = threadIdx.x;
    const int lane = tid & 63;
    const int w    = tid >> 6;                // wave 0..3
    const int b0   = blockIdx.x * TILE;       // bill base
    const int n0   = blockIdx.y * TILE;       // politician base
    const int wr   = (w >> 1) * 32;           // wave's pol offset in tile
    const int wc   = (w & 1) * 32;            // wave's bill offset in tile
    const int l15  = lane & 15;
    const int l4   = lane >> 4;

    // ---- Events gather first (16 independent loads; latency hides under build).
    unsigned evb = 0u, vb = 0u;
#pragma unroll
    for (int nr = 0; nr < 2; ++nr)
#pragma unroll
    for (int bc = 0; bc < 2; ++bc)
#pragma unroll
    for (int r = 0; r < 4; ++r) {
        const int ng = n0 + wr + 16 * nr + l4 * 4 + r;
        const int bg = b0 + wc + 16 * bc + l15;
        const bool v = (ng < NN) && (bg < NB);
        const size_t idx = v ? ((size_t)ng * NB + bg) : 0;
        const unsigned bit = 1u << (nr * 8 + bc * 4 + r);
        if (v) vb |= bit;
        if (v && events[idx]) evb |= bit;
    }

    // ---- Phase A: data octets (0-11), zeros for 12-15 (oct 12 overwritten in C).
    for (int u = tid; u < NOCT * TILE; u += 256) {     // W side, coalesced
        const int oct = u >> 6, nl = u & 63;
        const int n = n0 + nl;
        half8 hv = {};
        if (oct < 12 && n < NN) {
            const float* src = zp + ((size_t)(oct >> 2) * NN + n) * DD + 8 * (oct & 3);
            const float4 x = ((const float4*)src)[0];
            const float4 y = ((const float4*)src)[1];
            hv[0] = (_Float16)x.x; hv[1] = (_Float16)x.y;
            hv[2] = (_Float16)x.z; hv[3] = (_Float16)x.w;
            hv[4] = (_Float16)y.x; hv[5] = (_Float16)y.y;
            hv[6] = (_Float16)y.z; hv[7] = (_Float16)y.w;
        }
        *(half8*)(sW + (size_t)u * 8) = hv;
    }
    for (int u = tid; u < NOCT * TILE; u += 256) {     // Zf side, coalesced
        const int oct = u >> 6, bl = u & 63;
        const int b = b0 + bl;
        half8 hv = {};
        if (oct < 12 && b < NB) {
            const float t = tarr[b];
            const float s = (oct < 4) ? 1.f : (oct < 8) ? t : 0.5f * t * t;
            const float* src = zb + (size_t)b * DD + 8 * (oct & 3);
            const float4 x = ((const float4*)src)[0];
            const float4 y = ((const float4*)src)[1];
            hv[0] = (_Float16)(s * x.x); hv[1] = (_Float16)(s * x.y);
            hv[2] = (_Float16)(s * x.z); hv[3] = (_Float16)(s * x.w);
            hv[4] = (_Float16)(s * y.x); hv[5] = (_Float16)(s * y.y);
            hv[6] = (_Float16)(s * y.z); hv[7] = (_Float16)(s * y.w);
        }
        *(half8*)(sZ + (size_t)u * 8) = hv;
    }

    // ---- Phase B: cooperative partial dots, 4 threads/row x 8 dims (coalesced).
    {
        const int nl = tid >> 2, q = tid & 3;
        const int n = n0 + nl;
        float aa = 0.f, ab = 0.f, ac = 0.f, bb = 0.f, bc2 = 0.f, cc6 = 0.f;
        if (n < NN) {
            const float* pA = zp + (size_t)n * DD + 8 * q;
            const float* pB = zp + ((size_t)NN + n) * DD + 8 * q;
            const float* pC = zp + ((size_t)2 * NN + n) * DD + 8 * q;
#pragma unroll
            for (int d = 0; d < 8; ++d) {
                const float a = pA[d], b = pB[d], c = pC[d];
                aa = fmaf(a, a, aa); ab = fmaf(a, b, ab); ac = fmaf(a, c, ac);
                bb = fmaf(b, b, bb); bc2 = fmaf(b, c, bc2); cc6 = fmaf(c, c, cc6);
            }
        }
        sT[nl][q][0] = aa;  sT[nl][q][1] = ab;  sT[nl][q][2] = ac;
        sT[nl][q][3] = bb;  sT[nl][q][4] = bc2; sT[nl][q][5] = cc6;
    }
    {
        const int bl = tid >> 2, q = tid & 3;
        const int b = b0 + bl;
        float z2p = 0.f;
        if (b < NB) {
            const float* zr = zb + (size_t)b * DD + 8 * q;
#pragma unroll
            for (int d = 0; d < 8; ++d) z2p = fmaf(zr[d], zr[d], z2p);
        }
        sT2[bl][q] = z2p;
    }
    __syncthreads();

    // ---- Phase C: combine partials -> poly octet 12 rows.
    if (tid < TILE) {                       // W poly row for pol tid
        const int nl = tid;
        float c6[6];
#pragma unroll
        for (int i = 0; i < 6; ++i)
            c6[i] = (sT[nl][0][i] + sT[nl][1][i]) + (sT[nl][2][i] + sT[nl][3][i]);
        half8 hv = {};
        hv[0] = (_Float16)c6[0];            // aa
        hv[1] = (_Float16)(2.f * c6[1]);    // 2 A.B
        hv[2] = (_Float16)(c6[3] + c6[2]);  // |B|^2 + A.C
        hv[3] = (_Float16)c6[4];            // B.C
        hv[4] = (_Float16)(0.25f * c6[5]);  // |C|^2/4
        hv[5] = (_Float16)1.f;
        *(half8*)(sW + ((size_t)12 * TILE + nl) * 8) = hv;
    } else if (tid < 2 * TILE) {            // Zf poly row for bill tid-64
        const int bl = tid - TILE;
        const int b = b0 + bl;
        const float z2 = (sT2[bl][0] + sT2[bl][1]) + (sT2[bl][2] + sT2[bl][3]);
        const float t = (b < NB) ? tarr[b] : 0.f;
        const float t2 = t * t;
        half8 hv = {};
        hv[0] = (_Float16)(-0.5f);
        hv[1] = (_Float16)(-0.5f * t);
        hv[2] = (_Float16)(-0.5f * t2);
        hv[3] = (_Float16)(-0.5f * t2 * t);
        hv[4] = (_Float16)(-0.5f * t2 * t2);
        hv[5] = (_Float16)(-0.5f * z2);
        *(half8*)(sZ + ((size_t)12 * TILE + bl) * 8) = hv;
    }
    __syncthreads();

    // ---- Fragment loads from LDS (K=128: 4 K-steps).
    half8 af[2][4], bf[2][4];
#pragma unroll
    for (int ks = 0; ks < 4; ++ks) {
        const int oct = 4 * ks + l4;
#pragma unroll
        for (int h = 0; h < 2; ++h) {
            af[h][ks] = *(const half8*)(sW + ((size_t)oct * TILE + wr + 16 * h + l15) * 8);
            bf[h][ks] = *(const half8*)(sZ + ((size_t)oct * TILE + wc + 16 * h + l15) * 8);
        }
    }

    float4v acc[2][2] = {};
#pragma unroll
    for (int nr = 0; nr < 2; ++nr)
#pragma unroll
    for (int bc = 0; bc < 2; ++bc)
#pragma unroll
    for (int ks = 0; ks < 4; ++ks)
        acc[nr][bc] = __builtin_amdgcn_mfma_f32_16x16x32_f16(
            af[nr][ks], bf[bc][ks], acc[nr][bc], 0, 0, 0);

    // ---- Epilogue: acc = -dist^2/2;  L = gamma + beta - dist.
    float accs = 0.f;
#pragma unroll
    for (int bc = 0; bc < 2; ++bc) {
        const int bg = b0 + wc + 16 * bc + l15;
        const float be = beta[bg < NB ? bg : 0];          // coalesced
#pragma unroll
        for (int nr = 0; nr < 2; ++nr) {
#pragma unroll
            for (int r = 0; r < 4; ++r) {
                const int ng = n0 + wr + 16 * nr + l4 * 4 + r;
                const float g = gamma[ng < NN ? ng : 0];  // group-broadcast
                const float d2 = fmaxf(-2.f * acc[nr][bc][r], 0.f);
                const float L  = g + be - sqrtf(d2);
                const unsigned bit = 1u << (nr * 8 + bc * 4 + r);
                const float sgn = (evb & bit) ? 1.f : -1.f;
                const float s   = sgn * L;
                const float term = fmaxf(-s, 0.f) + __logf(1.f + __expf(-fabsf(s)));
                accs += (vb & bit) ? term : 0.f;
            }
        }
    }

    // ---- Block partial.
#pragma unroll
    for (int o = 32; o > 0; o >>= 1) accs += __shfl_down(accs, o, 64);
    if (lane == 0) s_red[w] = accs;
    __syncthreads();
    if (tid == 0)
        partials[blockIdx.y * GDIM + blockIdx.x] =
            (s_red[0] + s_red[1]) + (s_red[2] + s_red[3]);
}

// Reduce: 1024 partials -> d_out[0] (overwrite; poison-proof).
__global__ __launch_bounds__(256) void pol2vec_reduce(
    const float4* __restrict__ p4, float* __restrict__ out)
{
    __shared__ float s_red[4];
    const int tid = threadIdx.x;
    const float4 v = p4[tid];                 // 256 threads x float4 = 1024
    float s = (v.x + v.y) + (v.z + v.w);
#pragma unroll
    for (int o = 32; o > 0; o >>= 1) s += __shfl_down(s, o, 64);
    if ((tid & 63) == 0) s_red[tid >> 6] = s;
    __syncthreads();
    if (tid == 0) out[0] = (s_red[0] + s_red[1]) + (s_red[2] + s_red[3]);
}

extern "C" void kernel_launch(void* const* d_in, const int* in_sizes, int n_in,
                              void* d_out, int out_size, void* d_ws, size_t ws_size,
                              hipStream_t stream) {
    const int*   events = (const int*)d_in[0];    // [N,B]
    const float* tarr   = (const float*)d_in[1];  // [B]
    const float* beta   = (const float*)d_in[2];  // [B]
    const float* gamma  = (const float*)d_in[3];  // [N]
    const float* zb     = (const float*)d_in[4];  // [B,D]
    const float* zp     = (const float*)d_in[5];  // [K,N,D]
    float* out = (float*)d_out;

    float* parts = (float*)d_ws;                  // [NPART], overwritten

    dim3 grid(GDIM, GDIM);
    pol2vec_main<<<grid, 256, 0, stream>>>(events, tarr, beta, gamma, zb, zp,
                                           parts);
    pol2vec_reduce<<<1, 256, 0, stream>>>((const float4*)parts, out);
}